// Round 7
// baseline (538.758 us; speedup 1.0000x reference)
//
#include <hip/hip_runtime.h>
#include <cstddef>

// ---------------------------------------------------------------------------
// GCN 2-layer forward. Round 10:
//  - GEMM: __launch_bounds__(256, 4) — rounds 4-9 were pinned at ~2 resident
//    blocks/CU (Occupancy 17%) by the min-waves/EU=2 declaration while VGPR
//    (100) and LDS (32 KB) allow 5. 4 blocks/CU -> all 782 blocks co-resident,
//    2x waves/SIMD for latency hiding, no tail round.
//  - Launch-count 13 -> 10: hipMemsetAsync replaces k_zero; dinv+scan+expand
//    fused (per-block redundant scan of the <=256-entry chunk_sum); both
//    weight packs in one kernel. (~10 us/dispatch overhead observed.)
//  - Structure otherwise = round 9: A reg-pipelined through 32 KB LDS with
//    cvt_pk bf16 hi/lo split; B pre-packed fragment-major, L2-direct;
//    fp16 xw1 gather; agg kernels unchanged.
// ---------------------------------------------------------------------------

typedef __attribute__((ext_vector_type(8))) short short8;
typedef __attribute__((ext_vector_type(4))) float f32x4;
typedef __attribute__((ext_vector_type(4))) _Float16 half4;

__device__ inline unsigned short f2bf(float f) {
    unsigned u = __float_as_uint(f);
    unsigned r = (u + 0x7fffu + ((u >> 16) & 1u)) >> 16;  // RNE
    return (unsigned short)r;
}
__device__ inline float bf2f(unsigned short h) {
    return __uint_as_float((unsigned)h << 16);
}

// packs bf16(a) into [15:0], bf16(b) into [31:16]
__device__ inline unsigned cvt_pk_bf16(float a, float b) {
    unsigned r;
    asm("v_cvt_pk_bf16_f32 %0, %1, %2" : "=v"(r) : "v"(a), "v"(b));
    return r;
}

__global__ void k_edge_hist(const int* __restrict__ dst, int* __restrict__ cnt, int E) {
    int e = blockIdx.x * blockDim.x + threadIdx.x;
    if (e < E) atomicAdd(&cnt[dst[e]], 1);
}

__device__ inline int wave_incl_scan(int v) {
    const int lane = threadIdx.x & 63;
#pragma unroll
    for (int off = 1; off < 64; off <<= 1) {
        int u = __shfl_up(v, off);
        if (lane >= off) v += u;
    }
    return v;
}

__global__ __launch_bounds__(256) void k_chunk_sum(const int* __restrict__ cnt,
                                                   int* __restrict__ chunk_sum, int N) {
    __shared__ int wsum[4];
    const int i = blockIdx.x * 256 + threadIdx.x;
    int v = (i < N) ? cnt[i] : 0;
#pragma unroll
    for (int off = 32; off > 0; off >>= 1) v += __shfl_xor(v, off);
    if ((threadIdx.x & 63) == 0) wsum[threadIdx.x >> 6] = v;
    __syncthreads();
    if (threadIdx.x == 0)
        chunk_sum[blockIdx.x] = wsum[0] + wsum[1] + wsum[2] + wsum[3];
}

// Fused: scan of chunk_sum (redundant per block, CH<=256) + within-chunk
// exclusive scan -> row_start/cursor, + dinv.
__global__ __launch_bounds__(256) void k_expand_fused(
    const int* __restrict__ cnt, const int* __restrict__ chunk_sum,
    int* __restrict__ row_start, int* __restrict__ cursor,
    float* __restrict__ dinv, int N, int E, int CH) {
    __shared__ int wsum[4];
    __shared__ int base_sh;
    const int t = threadIdx.x, lane = t & 63, wid = t >> 6;

    // Pass 1: every block scans chunk_sum[0..CH) and keeps its own base.
    int v = (t < CH) ? chunk_sum[t] : 0;
    int incl = wave_incl_scan(v);
    if (lane == 63) wsum[wid] = incl;
    __syncthreads();
    int cb = 0;
    for (int w2 = 0; w2 < 4; ++w2) { int s = wsum[w2]; if (w2 < wid) cb += s; }
    if (t == (int)blockIdx.x) base_sh = cb + incl - v;
    __syncthreads();                 // all wsum reads done; base_sh visible
    const int base0 = base_sh;

    // Pass 2: expand within this chunk (+ fused dinv).
    const int i = blockIdx.x * 256 + t;
    int c = (i < N) ? cnt[i] : 0;
    int incl2 = wave_incl_scan(c);
    if (lane == 63) wsum[wid] = incl2;
    __syncthreads();
    int b = base0;
    for (int w2 = 0; w2 < 4; ++w2) { int s = wsum[w2]; if (w2 < wid) b += s; }
    const int excl = b + incl2 - c;
    if (i < N) {
        row_start[i] = excl;
        cursor[i]    = excl;
        dinv[i]      = rsqrtf((float)(c + 1));   // +1 self-loop
    }
    if (i == 0) row_start[N] = E;
}

__global__ void k_fill_csr(const int* __restrict__ src, const int* __restrict__ dst,
                           const float* __restrict__ dinv,
                           int* __restrict__ cursor, int* __restrict__ csr_src,
                           float* __restrict__ csr_w, int E) {
    int e = blockIdx.x * blockDim.x + threadIdx.x;
    if (e < E) {
        const int d = dst[e];
        const int s = src[e];
        const int p = atomicAdd(&cursor[d], 1);
        csr_src[p] = s;
        csr_w[p]   = dinv[s] * dinv[d];
    }
}

// Fragment-major pack of BOTH weight matrices in one launch.
// P[nf][K/32][lane][8], lane = (k>>3 & 3)*16 + (n&15), elem j = k&7.
__device__ inline void pack_one(const float* __restrict__ W,
                                unsigned short* __restrict__ Ph,
                                unsigned short* __restrict__ Pl,
                                int i, int K, int N) {
    const int k = i / N, n = i % N;
    const float v = W[i];
    const unsigned short h = f2bf(v);
    const unsigned short l = f2bf(v - bf2f(h));
    const int nf = n >> 4, l15 = n & 15;
    const int kb = k >> 5, l4 = (k >> 3) & 3, j = k & 7;
    const size_t dst = ((((size_t)nf * (K >> 5) + kb) * 64) + l4 * 16 + l15) * 8 + j;
    Ph[dst] = h;
    Pl[dst] = l;
}

__global__ void k_pack_both(const float* __restrict__ W1,
                            unsigned short* __restrict__ P1h,
                            unsigned short* __restrict__ P1l,
                            const float* __restrict__ W2,
                            unsigned short* __restrict__ P2h,
                            unsigned short* __restrict__ P2l) {
    const int i = blockIdx.x * blockDim.x + threadIdx.x;
    constexpr int S1 = 512 * 256;
    constexpr int S2 = 256 * 64;
    if (i < S1)            pack_one(W1, P1h, P1l, i, 512, 256);
    else if (i < S1 + S2)  pack_one(W2, P2h, P2l, i - S1, 256, 64);
}

// C[M,N] = A[M,K] @ B[K,N], bf16x2-split MFMA.
// A: f32 row-major, reg-pipelined + staged to LDS (cvt_pk split, swizzled).
// B: packed fragment-major bf16 hi/lo (k_pack_both), loaded direct (L2).
// 256 threads = 4 waves 2x2; wave tile = 64 x (BN/2); BK = 64.
template<int BN, bool F16OUT>
__global__ __launch_bounds__(256, 4) void k_gemm_mfma(
    const float* __restrict__ A,
    const unsigned short* __restrict__ Bph,
    const unsigned short* __restrict__ Bpl,
    void* __restrict__ Cv, int M, int N, int K) {
    constexpr int BM  = 128, BK = 64;
    constexpr int MF  = 4;                    // 4 x 16 rows per wave
    constexpr int NF  = BN / 32;              // frags over wave's BN/2 cols
    constexpr int NA4 = BM * BK / 4 / 256;    // 8 float4 per thread (A tile)

    __shared__ unsigned short Ash[BM * BK];
    __shared__ unsigned short Asl[BM * BK];

    const int t    = threadIdx.x;
    const int lane = t & 63;
    const int w    = t >> 6;
    const int wr   = w >> 1;      // 0..1
    const int wc   = w & 1;       // 0..1
    const int l15  = lane & 15;
    const int l4   = lane >> 4;
    const int bm   = blockIdx.x * BM;
    const int bn   = blockIdx.y * BN;

    const int K32     = K >> 5;
    const int nf_base = (bn + wc * (BN / 2)) >> 4;

    f32x4 acc[MF][NF] = {};

    float4 araw[NA4];   // raw A tile one K-step ahead

    auto issue_loads = [&](int k0) {
#pragma unroll
        for (int i = 0; i < NA4; ++i) {
            const int idx = t + i * 256;
            const int ar  = idx >> 4;         // 0..BM-1
            const int ac  = (idx & 15) * 4;   // 0..60
            const int am  = bm + ar;
            araw[i] = (am < M) ? *(const float4*)(A + (size_t)am * K + k0 + ac)
                               : make_float4(0.f, 0.f, 0.f, 0.f);
        }
    };

    auto stage_to_lds = [&]() {
#pragma unroll
        for (int i = 0; i < NA4; ++i) {
            const int idx = t + i * 256;
            const int ar  = idx >> 4;
            const int ac  = (idx & 15) * 4;
            const float4 v = araw[i];
            const unsigned ph0 = cvt_pk_bf16(v.x, v.y);
            const unsigned ph1 = cvt_pk_bf16(v.z, v.w);
            const float h0 = __uint_as_float(ph0 << 16);
            const float h1 = __uint_as_float(ph0 & 0xffff0000u);
            const float h2 = __uint_as_float(ph1 << 16);
            const float h3 = __uint_as_float(ph1 & 0xffff0000u);
            const unsigned pl0 = cvt_pk_bf16(v.x - h0, v.y - h1);
            const unsigned pl1 = cvt_pk_bf16(v.z - h2, v.w - h3);
            const int si = (ar * BK + ac) ^ ((ar & 7) << 3);
            *(uint2*)&Ash[si] = make_uint2(ph0, ph1);
            *(uint2*)&Asl[si] = make_uint2(pl0, pl1);
        }
    };

    const int NT = K / BK;
    issue_loads(0);
    for (int ts = 0; ts < NT; ++ts) {
        stage_to_lds();                              // consumes raw tile ts
        if (ts + 1 < NT) issue_loads((ts + 1) * BK); // in flight across MFMA
        __syncthreads();

        const int k0 = ts * BK;
#pragma unroll
        for (int kk = 0; kk < BK; kk += 32) {
            const int kb   = kk + l4 * 8;        // A LDS k-offset
            const int kb32 = (k0 + kk) >> 5;     // packed-B K/32 index
            short8 bh[NF], bl[NF];
#pragma unroll
            for (int n = 0; n < NF; ++n) {
                const size_t boff =
                    (((size_t)(nf_base + n) * K32 + kb32) * 64 + lane) * 8;
                bh[n] = *(const short8*)(Bph + boff);
                bl[n] = *(const short8*)(Bpl + boff);
            }
#pragma unroll
            for (int m = 0; m < MF; ++m) {
                const int row = wr * 64 + m * 16 + l15;
                const int si  = (row * BK + kb) ^ ((row & 7) << 3);
                const short8 ah = *(const short8*)&Ash[si];
                const short8 al = *(const short8*)&Asl[si];
#pragma unroll
                for (int n = 0; n < NF; ++n) {
                    acc[m][n] = __builtin_amdgcn_mfma_f32_16x16x32_bf16(ah, bh[n], acc[m][n], 0, 0, 0);
                    acc[m][n] = __builtin_amdgcn_mfma_f32_16x16x32_bf16(ah, bl[n], acc[m][n], 0, 0, 0);
                    acc[m][n] = __builtin_amdgcn_mfma_f32_16x16x32_bf16(al, bh[n], acc[m][n], 0, 0, 0);
                }
            }
        }
        __syncthreads();
    }

    // ---- epilogue: C/D layout col = lane&15, row = (lane>>4)*4 + e ----
#pragma unroll
    for (int m = 0; m < MF; ++m) {
        const int row0 = bm + wr * 64 + m * 16 + l4 * 4;
#pragma unroll
        for (int e = 0; e < 4; ++e) {
            const int r = row0 + e;
            if (r < M) {
#pragma unroll
                for (int n = 0; n < NF; ++n) {
                    const size_t ci = (size_t)r * N + bn + wc * (BN / 2) + n * 16 + l15;
                    if constexpr (F16OUT)
                        ((_Float16*)Cv)[ci] = (_Float16)acc[m][n][e];
                    else
                        ((float*)Cv)[ci] = acc[m][n][e];
                }
            }
        }
    }
}

// Layer-1 aggregate: one wave per dst node, F=256, fp16 input (lane -> half4),
// f32 accumulate, unroll x4, f32 output.
__global__ __launch_bounds__(256) void k_agg256_relu(
    const int* __restrict__ row_start, const int* __restrict__ csr_src,
    const float* __restrict__ csr_w, const float* __restrict__ dinv,
    const _Float16* __restrict__ xw, const float* __restrict__ bias,
    float* __restrict__ out, int N) {
    const int node = blockIdx.x * 4 + (threadIdx.x >> 6);
    const int lane = threadIdx.x & 63;
    if (node >= N) return;

    const float dn  = dinv[node];
    const int   beg = row_start[node];
    const int   end = row_start[node + 1];

    const half4 hs = *(const half4*)(xw + (size_t)node * 256 + lane * 4);
    const float wself = dn * dn;
    float4 acc;
    acc.x = (float)hs.x * wself; acc.y = (float)hs.y * wself;
    acc.z = (float)hs.z * wself; acc.w = (float)hs.w * wself;

    int j = beg;
    const int end4 = beg + ((end - beg) & ~3);
    for (; j < end4; j += 4) {
        const int s0 = csr_src[j + 0], s1 = csr_src[j + 1];
        const int s2 = csr_src[j + 2], s3 = csr_src[j + 3];
        const float w0 = csr_w[j + 0], w1 = csr_w[j + 1];
        const float w2 = csr_w[j + 2], w3 = csr_w[j + 3];
        const half4 v0 = *(const half4*)(xw + (size_t)s0 * 256 + lane * 4);
        const half4 v1 = *(const half4*)(xw + (size_t)s1 * 256 + lane * 4);
        const half4 v2 = *(const half4*)(xw + (size_t)s2 * 256 + lane * 4);
        const half4 v3 = *(const half4*)(xw + (size_t)s3 * 256 + lane * 4);
        acc.x = fmaf((float)v0.x, w0, acc.x); acc.y = fmaf((float)v0.y, w0, acc.y);
        acc.z = fmaf((float)v0.z, w0, acc.z); acc.w = fmaf((float)v0.w, w0, acc.w);
        acc.x = fmaf((float)v1.x, w1, acc.x); acc.y = fmaf((float)v1.y, w1, acc.y);
        acc.z = fmaf((float)v1.z, w1, acc.z); acc.w = fmaf((float)v1.w, w1, acc.w);
        acc.x = fmaf((float)v2.x, w2, acc.x); acc.y = fmaf((float)v2.y, w2, acc.y);
        acc.z = fmaf((float)v2.z, w2, acc.z); acc.w = fmaf((float)v2.w, w2, acc.w);
        acc.x = fmaf((float)v3.x, w3, acc.x); acc.y = fmaf((float)v3.y, w3, acc.y);
        acc.z = fmaf((float)v3.z, w3, acc.z); acc.w = fmaf((float)v3.w, w3, acc.w);
    }
    for (; j < end; ++j) {
        const int   s = csr_src[j];
        const float w = csr_w[j];
        const half4 v = *(const half4*)(xw + (size_t)s * 256 + lane * 4);
        acc.x = fmaf((float)v.x, w, acc.x); acc.y = fmaf((float)v.y, w, acc.y);
        acc.z = fmaf((float)v.z, w, acc.z); acc.w = fmaf((float)v.w, w, acc.w);
    }

    const float4 b = ((const float4*)bias)[lane];
    acc.x = fmaxf(acc.x + b.x, 0.f);
    acc.y = fmaxf(acc.y + b.y, 0.f);
    acc.z = fmaxf(acc.z + b.z, 0.f);
    acc.w = fmaxf(acc.w + b.w, 0.f);
    *(float4*)(out + (size_t)node * 256 + lane * 4) = acc;
}

// Layer-2 aggregate + bias + softmax: one wave per dst node, F=64, unroll x4.
__global__ __launch_bounds__(256) void k_agg64_softmax(
    const int* __restrict__ row_start, const int* __restrict__ csr_src,
    const float* __restrict__ csr_w, const float* __restrict__ dinv,
    const float* __restrict__ xw, const float* __restrict__ bias,
    float* __restrict__ out, int N) {
    const int node = blockIdx.x * 4 + (threadIdx.x >> 6);
    const int lane = threadIdx.x & 63;
    if (node >= N) return;

    const float dn  = dinv[node];
    const int   beg = row_start[node];
    const int   end = row_start[node + 1];

    float acc = xw[(size_t)node * 64 + lane] * dn * dn;
    int j = beg;
    const int end4 = beg + ((end - beg) & ~3);
    for (; j < end4; j += 4) {
        const int s0 = csr_src[j + 0], s1 = csr_src[j + 1];
        const int s2 = csr_src[j + 2], s3 = csr_src[j + 3];
        const float w0 = csr_w[j + 0], w1 = csr_w[j + 1];
        const float w2 = csr_w[j + 2], w3 = csr_w[j + 3];
        const float v0 = xw[(size_t)s0 * 64 + lane];
        const float v1 = xw[(size_t)s1 * 64 + lane];
        const float v2 = xw[(size_t)s2 * 64 + lane];
        const float v3 = xw[(size_t)s3 * 64 + lane];
        acc = fmaf(v0, w0, acc);
        acc = fmaf(v1, w1, acc);
        acc = fmaf(v2, w2, acc);
        acc = fmaf(v3, w3, acc);
    }
    for (; j < end; ++j)
        acc = fmaf(xw[(size_t)csr_src[j] * 64 + lane], csr_w[j], acc);

    acc += bias[lane];

    float m = acc;
#pragma unroll
    for (int o = 32; o > 0; o >>= 1) m = fmaxf(m, __shfl_xor(m, o));
    const float e = expf(acc - m);
    float s = e;
#pragma unroll
    for (int o = 32; o > 0; o >>= 1) s += __shfl_xor(s, o);
    out[(size_t)node * 64 + lane] = e / s;
}

extern "C" void kernel_launch(void* const* d_in, const int* in_sizes, int n_in,
                              void* d_out, int out_size, void* d_ws, size_t ws_size,
                              hipStream_t stream) {
    const float* x  = (const float*)d_in[0];
    const int*   ei = (const int*)d_in[1];
    const float* W1 = (const float*)d_in[2];
    const float* b1 = (const float*)d_in[3];
    const float* W2 = (const float*)d_in[4];
    const float* b2 = (const float*)d_in[5];
    float* out = (float*)d_out;

    const int E = in_sizes[1] / 2;   // 800000
    const int N = out_size / 64;     // 50000
    const int* src = ei;
    const int* dst = ei + E;
    const int CH = (N + 255) / 256;  // 196 chunks

    char* ws = (char*)d_ws;
    size_t o = 0;
    auto alloc = [&](size_t bytes) {
        void* p = ws + o;
        o += (bytes + 255) & ~(size_t)255;
        return p;
    };
    int*   cnt        = (int*)alloc((size_t)N * 4);
    int*   chunk_sum  = (int*)alloc((size_t)256 * 4);
    int*   row_start  = (int*)alloc((size_t)(N + 1) * 4);
    int*   cursor     = (int*)alloc((size_t)N * 4);
    int*   csr_src    = (int*)alloc((size_t)E * 4);
    float* csr_w      = (float*)alloc((size_t)E * 4);
    float* dinv       = (float*)alloc((size_t)N * 4);
    _Float16* xw1     = (_Float16*)alloc((size_t)N * 256 * 2);
    float* h1         = (float*)alloc((size_t)N * 256 * 4);
    float* xw2        = (float*)alloc((size_t)N * 64 * 4);
    unsigned short* wt1h = (unsigned short*)alloc((size_t)256 * 512 * 2);
    unsigned short* wt1l = (unsigned short*)alloc((size_t)256 * 512 * 2);
    unsigned short* wt2h = (unsigned short*)alloc((size_t)64 * 256 * 2);
    unsigned short* wt2l = (unsigned short*)alloc((size_t)64 * 256 * 2);
    (void)ws_size; (void)n_in;

    // ---- CSR build + dinv + weight pack (10 stream ops total) ----
    hipMemsetAsync(cnt, 0, (size_t)N * 4, stream);
    k_edge_hist<<<(E + 255) / 256, 256, 0, stream>>>(dst, cnt, E);
    k_chunk_sum<<<CH, 256, 0, stream>>>(cnt, chunk_sum, N);
    k_expand_fused<<<CH, 256, 0, stream>>>(cnt, chunk_sum, row_start, cursor, dinv, N, E, CH);
    k_fill_csr<<<(E + 255) / 256, 256, 0, stream>>>(src, dst, dinv, cursor, csr_src, csr_w, E);
    k_pack_both<<<(512 * 256 + 256 * 64 + 255) / 256, 256, 0, stream>>>(
        W1, wt1h, wt1l, W2, wt2h, wt2l);

    // ---- layer 1: xw1 = x @ W1 (MFMA split, fp16 out), aggregate+ReLU ----
    dim3 g1((N + 127) / 128, 2);
    k_gemm_mfma<128, true><<<g1, 256, 0, stream>>>(x, wt1h, wt1l, xw1, N, 256, 512);
    k_agg256_relu<<<(N + 3) / 4, 256, 0, stream>>>(row_start, csr_src, csr_w, dinv, xw1, b1, h1, N);

    // ---- layer 2: xw2 = h1 @ W2 (MFMA split), aggregate+softmax ----
    dim3 g2((N + 127) / 128, 1);
    k_gemm_mfma<64, false><<<g2, 256, 0, stream>>>(h1, wt2h, wt2l, xw2, N, 64, 256);
    k_agg64_softmax<<<(N + 3) / 4, 256, 0, stream>>>(row_start, csr_src, csr_w, dinv, xw2, b2, out, N);
}

// Round 8
// 431.861 us; speedup vs baseline: 1.2475x; 1.2475x over previous
//
#include <hip/hip_runtime.h>
#include <cstddef>

// ---------------------------------------------------------------------------
// GCN 2-layer forward. Round 11:
//  - Round 10 post-mortem: __launch_bounds__(256,4) forced VGPR cap to 64 ->
//    accumulator spilled to scratch (WRITE 25->264 MB, FETCH 103->314 MB,
//    GEMM 75->213 us). Occupancy mechanism itself worked (17->32%).
//  - Fix: __launch_bounds__(256,3): VGPR cap ~168 > the 100 the allocator
//    wants (no spills), 3 blocks/CU resident -> whole 782-block grid
//    co-resident in one pass, 12 waves/CU latency hiding.
//  - Keeps: 32 KB A-only LDS (cvt_pk bf16 hi/lo, swizzled, reg-pipelined
//    one K-tile ahead); B pre-packed fragment-major, L2-direct; fp16 xw1
//    gather; memset/fused-expand/single-pack launch reductions.
// ---------------------------------------------------------------------------

typedef __attribute__((ext_vector_type(8))) short short8;
typedef __attribute__((ext_vector_type(4))) float f32x4;
typedef __attribute__((ext_vector_type(4))) _Float16 half4;

__device__ inline unsigned short f2bf(float f) {
    unsigned u = __float_as_uint(f);
    unsigned r = (u + 0x7fffu + ((u >> 16) & 1u)) >> 16;  // RNE
    return (unsigned short)r;
}
__device__ inline float bf2f(unsigned short h) {
    return __uint_as_float((unsigned)h << 16);
}

// packs bf16(a) into [15:0], bf16(b) into [31:16]
__device__ inline unsigned cvt_pk_bf16(float a, float b) {
    unsigned r;
    asm("v_cvt_pk_bf16_f32 %0, %1, %2" : "=v"(r) : "v"(a), "v"(b));
    return r;
}

__global__ void k_edge_hist(const int* __restrict__ dst, int* __restrict__ cnt, int E) {
    int e = blockIdx.x * blockDim.x + threadIdx.x;
    if (e < E) atomicAdd(&cnt[dst[e]], 1);
}

__device__ inline int wave_incl_scan(int v) {
    const int lane = threadIdx.x & 63;
#pragma unroll
    for (int off = 1; off < 64; off <<= 1) {
        int u = __shfl_up(v, off);
        if (lane >= off) v += u;
    }
    return v;
}

__global__ __launch_bounds__(256) void k_chunk_sum(const int* __restrict__ cnt,
                                                   int* __restrict__ chunk_sum, int N) {
    __shared__ int wsum[4];
    const int i = blockIdx.x * 256 + threadIdx.x;
    int v = (i < N) ? cnt[i] : 0;
#pragma unroll
    for (int off = 32; off > 0; off >>= 1) v += __shfl_xor(v, off);
    if ((threadIdx.x & 63) == 0) wsum[threadIdx.x >> 6] = v;
    __syncthreads();
    if (threadIdx.x == 0)
        chunk_sum[blockIdx.x] = wsum[0] + wsum[1] + wsum[2] + wsum[3];
}

// Fused: scan of chunk_sum (redundant per block, CH<=256) + within-chunk
// exclusive scan -> row_start/cursor, + dinv.
__global__ __launch_bounds__(256) void k_expand_fused(
    const int* __restrict__ cnt, const int* __restrict__ chunk_sum,
    int* __restrict__ row_start, int* __restrict__ cursor,
    float* __restrict__ dinv, int N, int E, int CH) {
    __shared__ int wsum[4];
    __shared__ int base_sh;
    const int t = threadIdx.x, lane = t & 63, wid = t >> 6;

    // Pass 1: every block scans chunk_sum[0..CH) and keeps its own base.
    int v = (t < CH) ? chunk_sum[t] : 0;
    int incl = wave_incl_scan(v);
    if (lane == 63) wsum[wid] = incl;
    __syncthreads();
    int cb = 0;
    for (int w2 = 0; w2 < 4; ++w2) { int s = wsum[w2]; if (w2 < wid) cb += s; }
    if (t == (int)blockIdx.x) base_sh = cb + incl - v;
    __syncthreads();                 // all wsum reads done; base_sh visible
    const int base0 = base_sh;

    // Pass 2: expand within this chunk (+ fused dinv).
    const int i = blockIdx.x * 256 + t;
    int c = (i < N) ? cnt[i] : 0;
    int incl2 = wave_incl_scan(c);
    if (lane == 63) wsum[wid] = incl2;
    __syncthreads();
    int b = base0;
    for (int w2 = 0; w2 < 4; ++w2) { int s = wsum[w2]; if (w2 < wid) b += s; }
    const int excl = b + incl2 - c;
    if (i < N) {
        row_start[i] = excl;
        cursor[i]    = excl;
        dinv[i]      = rsqrtf((float)(c + 1));   // +1 self-loop
    }
    if (i == 0) row_start[N] = E;
}

__global__ void k_fill_csr(const int* __restrict__ src, const int* __restrict__ dst,
                           const float* __restrict__ dinv,
                           int* __restrict__ cursor, int* __restrict__ csr_src,
                           float* __restrict__ csr_w, int E) {
    int e = blockIdx.x * blockDim.x + threadIdx.x;
    if (e < E) {
        const int d = dst[e];
        const int s = src[e];
        const int p = atomicAdd(&cursor[d], 1);
        csr_src[p] = s;
        csr_w[p]   = dinv[s] * dinv[d];
    }
}

// Fragment-major pack of BOTH weight matrices in one launch.
// P[nf][K/32][lane][8], lane = (k>>3 & 3)*16 + (n&15), elem j = k&7.
__device__ inline void pack_one(const float* __restrict__ W,
                                unsigned short* __restrict__ Ph,
                                unsigned short* __restrict__ Pl,
                                int i, int K, int N) {
    const int k = i / N, n = i % N;
    const float v = W[i];
    const unsigned short h = f2bf(v);
    const unsigned short l = f2bf(v - bf2f(h));
    const int nf = n >> 4, l15 = n & 15;
    const int kb = k >> 5, l4 = (k >> 3) & 3, j = k & 7;
    const size_t dst = ((((size_t)nf * (K >> 5) + kb) * 64) + l4 * 16 + l15) * 8 + j;
    Ph[dst] = h;
    Pl[dst] = l;
}

__global__ void k_pack_both(const float* __restrict__ W1,
                            unsigned short* __restrict__ P1h,
                            unsigned short* __restrict__ P1l,
                            const float* __restrict__ W2,
                            unsigned short* __restrict__ P2h,
                            unsigned short* __restrict__ P2l) {
    const int i = blockIdx.x * blockDim.x + threadIdx.x;
    constexpr int S1 = 512 * 256;
    constexpr int S2 = 256 * 64;
    if (i < S1)            pack_one(W1, P1h, P1l, i, 512, 256);
    else if (i < S1 + S2)  pack_one(W2, P2h, P2l, i - S1, 256, 64);
}

// C[M,N] = A[M,K] @ B[K,N], bf16x2-split MFMA.
// A: f32 row-major, reg-pipelined + staged to LDS (cvt_pk split, swizzled).
// B: packed fragment-major bf16 hi/lo (k_pack_both), loaded direct (L2).
// 256 threads = 4 waves 2x2; wave tile = 64 x (BN/2); BK = 64.
template<int BN, bool F16OUT>
__global__ __launch_bounds__(256, 3) void k_gemm_mfma(
    const float* __restrict__ A,
    const unsigned short* __restrict__ Bph,
    const unsigned short* __restrict__ Bpl,
    void* __restrict__ Cv, int M, int N, int K) {
    constexpr int BM  = 128, BK = 64;
    constexpr int MF  = 4;                    // 4 x 16 rows per wave
    constexpr int NF  = BN / 32;              // frags over wave's BN/2 cols
    constexpr int NA4 = BM * BK / 4 / 256;    // 8 float4 per thread (A tile)

    __shared__ unsigned short Ash[BM * BK];
    __shared__ unsigned short Asl[BM * BK];

    const int t    = threadIdx.x;
    const int lane = t & 63;
    const int w    = t >> 6;
    const int wr   = w >> 1;      // 0..1
    const int wc   = w & 1;       // 0..1
    const int l15  = lane & 15;
    const int l4   = lane >> 4;
    const int bm   = blockIdx.x * BM;
    const int bn   = blockIdx.y * BN;

    const int K32     = K >> 5;
    const int nf_base = (bn + wc * (BN / 2)) >> 4;

    f32x4 acc[MF][NF] = {};

    float4 araw[NA4];   // raw A tile one K-step ahead

    auto issue_loads = [&](int k0) {
#pragma unroll
        for (int i = 0; i < NA4; ++i) {
            const int idx = t + i * 256;
            const int ar  = idx >> 4;         // 0..BM-1
            const int ac  = (idx & 15) * 4;   // 0..60
            const int am  = bm + ar;
            araw[i] = (am < M) ? *(const float4*)(A + (size_t)am * K + k0 + ac)
                               : make_float4(0.f, 0.f, 0.f, 0.f);
        }
    };

    auto stage_to_lds = [&]() {
#pragma unroll
        for (int i = 0; i < NA4; ++i) {
            const int idx = t + i * 256;
            const int ar  = idx >> 4;
            const int ac  = (idx & 15) * 4;
            const float4 v = araw[i];
            const unsigned ph0 = cvt_pk_bf16(v.x, v.y);
            const unsigned ph1 = cvt_pk_bf16(v.z, v.w);
            const float h0 = __uint_as_float(ph0 << 16);
            const float h1 = __uint_as_float(ph0 & 0xffff0000u);
            const float h2 = __uint_as_float(ph1 << 16);
            const float h3 = __uint_as_float(ph1 & 0xffff0000u);
            const unsigned pl0 = cvt_pk_bf16(v.x - h0, v.y - h1);
            const unsigned pl1 = cvt_pk_bf16(v.z - h2, v.w - h3);
            const int si = (ar * BK + ac) ^ ((ar & 7) << 3);
            *(uint2*)&Ash[si] = make_uint2(ph0, ph1);
            *(uint2*)&Asl[si] = make_uint2(pl0, pl1);
        }
    };

    const int NT = K / BK;
    issue_loads(0);
    for (int ts = 0; ts < NT; ++ts) {
        stage_to_lds();                              // consumes raw tile ts
        if (ts + 1 < NT) issue_loads((ts + 1) * BK); // in flight across MFMA
        __syncthreads();

        const int k0 = ts * BK;
#pragma unroll
        for (int kk = 0; kk < BK; kk += 32) {
            const int kb   = kk + l4 * 8;        // A LDS k-offset
            const int kb32 = (k0 + kk) >> 5;     // packed-B K/32 index
            short8 bh[NF], bl[NF];
#pragma unroll
            for (int n = 0; n < NF; ++n) {
                const size_t boff =
                    (((size_t)(nf_base + n) * K32 + kb32) * 64 + lane) * 8;
                bh[n] = *(const short8*)(Bph + boff);
                bl[n] = *(const short8*)(Bpl + boff);
            }
#pragma unroll
            for (int m = 0; m < MF; ++m) {
                const int row = wr * 64 + m * 16 + l15;
                const int si  = (row * BK + kb) ^ ((row & 7) << 3);
                const short8 ah = *(const short8*)&Ash[si];
                const short8 al = *(const short8*)&Asl[si];
#pragma unroll
                for (int n = 0; n < NF; ++n) {
                    acc[m][n] = __builtin_amdgcn_mfma_f32_16x16x32_bf16(ah, bh[n], acc[m][n], 0, 0, 0);
                    acc[m][n] = __builtin_amdgcn_mfma_f32_16x16x32_bf16(ah, bl[n], acc[m][n], 0, 0, 0);
                    acc[m][n] = __builtin_amdgcn_mfma_f32_16x16x32_bf16(al, bh[n], acc[m][n], 0, 0, 0);
                }
            }
        }
        __syncthreads();
    }

    // ---- epilogue: C/D layout col = lane&15, row = (lane>>4)*4 + e ----
#pragma unroll
    for (int m = 0; m < MF; ++m) {
        const int row0 = bm + wr * 64 + m * 16 + l4 * 4;
#pragma unroll
        for (int e = 0; e < 4; ++e) {
            const int r = row0 + e;
            if (r < M) {
#pragma unroll
                for (int n = 0; n < NF; ++n) {
                    const size_t ci = (size_t)r * N + bn + wc * (BN / 2) + n * 16 + l15;
                    if constexpr (F16OUT)
                        ((_Float16*)Cv)[ci] = (_Float16)acc[m][n][e];
                    else
                        ((float*)Cv)[ci] = acc[m][n][e];
                }
            }
        }
    }
}

// Layer-1 aggregate: one wave per dst node, F=256, fp16 input (lane -> half4),
// f32 accumulate, unroll x4, f32 output.
__global__ __launch_bounds__(256) void k_agg256_relu(
    const int* __restrict__ row_start, const int* __restrict__ csr_src,
    const float* __restrict__ csr_w, const float* __restrict__ dinv,
    const _Float16* __restrict__ xw, const float* __restrict__ bias,
    float* __restrict__ out, int N) {
    const int node = blockIdx.x * 4 + (threadIdx.x >> 6);
    const int lane = threadIdx.x & 63;
    if (node >= N) return;

    const float dn  = dinv[node];
    const int   beg = row_start[node];
    const int   end = row_start[node + 1];

    const half4 hs = *(const half4*)(xw + (size_t)node * 256 + lane * 4);
    const float wself = dn * dn;
    float4 acc;
    acc.x = (float)hs.x * wself; acc.y = (float)hs.y * wself;
    acc.z = (float)hs.z * wself; acc.w = (float)hs.w * wself;

    int j = beg;
    const int end4 = beg + ((end - beg) & ~3);
    for (; j < end4; j += 4) {
        const int s0 = csr_src[j + 0], s1 = csr_src[j + 1];
        const int s2 = csr_src[j + 2], s3 = csr_src[j + 3];
        const float w0 = csr_w[j + 0], w1 = csr_w[j + 1];
        const float w2 = csr_w[j + 2], w3 = csr_w[j + 3];
        const half4 v0 = *(const half4*)(xw + (size_t)s0 * 256 + lane * 4);
        const half4 v1 = *(const half4*)(xw + (size_t)s1 * 256 + lane * 4);
        const half4 v2 = *(const half4*)(xw + (size_t)s2 * 256 + lane * 4);
        const half4 v3 = *(const half4*)(xw + (size_t)s3 * 256 + lane * 4);
        acc.x = fmaf((float)v0.x, w0, acc.x); acc.y = fmaf((float)v0.y, w0, acc.y);
        acc.z = fmaf((float)v0.z, w0, acc.z); acc.w = fmaf((float)v0.w, w0, acc.w);
        acc.x = fmaf((float)v1.x, w1, acc.x); acc.y = fmaf((float)v1.y, w1, acc.y);
        acc.z = fmaf((float)v1.z, w1, acc.z); acc.w = fmaf((float)v1.w, w1, acc.w);
        acc.x = fmaf((float)v2.x, w2, acc.x); acc.y = fmaf((float)v2.y, w2, acc.y);
        acc.z = fmaf((float)v2.z, w2, acc.z); acc.w = fmaf((float)v2.w, w2, acc.w);
        acc.x = fmaf((float)v3.x, w3, acc.x); acc.y = fmaf((float)v3.y, w3, acc.y);
        acc.z = fmaf((float)v3.z, w3, acc.z); acc.w = fmaf((float)v3.w, w3, acc.w);
    }
    for (; j < end; ++j) {
        const int   s = csr_src[j];
        const float w = csr_w[j];
        const half4 v = *(const half4*)(xw + (size_t)s * 256 + lane * 4);
        acc.x = fmaf((float)v.x, w, acc.x); acc.y = fmaf((float)v.y, w, acc.y);
        acc.z = fmaf((float)v.z, w, acc.z); acc.w = fmaf((float)v.w, w, acc.w);
    }

    const float4 b = ((const float4*)bias)[lane];
    acc.x = fmaxf(acc.x + b.x, 0.f);
    acc.y = fmaxf(acc.y + b.y, 0.f);
    acc.z = fmaxf(acc.z + b.z, 0.f);
    acc.w = fmaxf(acc.w + b.w, 0.f);
    *(float4*)(out + (size_t)node * 256 + lane * 4) = acc;
}

// Layer-2 aggregate + bias + softmax: one wave per dst node, F=64, unroll x4.
__global__ __launch_bounds__(256) void k_agg64_softmax(
    const int* __restrict__ row_start, const int* __restrict__ csr_src,
    const float* __restrict__ csr_w, const float* __restrict__ dinv,
    const float* __restrict__ xw, const float* __restrict__ bias,
    float* __restrict__ out, int N) {
    const int node = blockIdx.x * 4 + (threadIdx.x >> 6);
    const int lane = threadIdx.x & 63;
    if (node >= N) return;

    const float dn  = dinv[node];
    const int   beg = row_start[node];
    const int   end = row_start[node + 1];

    float acc = xw[(size_t)node * 64 + lane] * dn * dn;
    int j = beg;
    const int end4 = beg + ((end - beg) & ~3);
    for (; j < end4; j += 4) {
        const int s0 = csr_src[j + 0], s1 = csr_src[j + 1];
        const int s2 = csr_src[j + 2], s3 = csr_src[j + 3];
        const float w0 = csr_w[j + 0], w1 = csr_w[j + 1];
        const float w2 = csr_w[j + 2], w3 = csr_w[j + 3];
        const float v0 = xw[(size_t)s0 * 64 + lane];
        const float v1 = xw[(size_t)s1 * 64 + lane];
        const float v2 = xw[(size_t)s2 * 64 + lane];
        const float v3 = xw[(size_t)s3 * 64 + lane];
        acc = fmaf(v0, w0, acc);
        acc = fmaf(v1, w1, acc);
        acc = fmaf(v2, w2, acc);
        acc = fmaf(v3, w3, acc);
    }
    for (; j < end; ++j)
        acc = fmaf(xw[(size_t)csr_src[j] * 64 + lane], csr_w[j], acc);

    acc += bias[lane];

    float m = acc;
#pragma unroll
    for (int o = 32; o > 0; o >>= 1) m = fmaxf(m, __shfl_xor(m, o));
    const float e = expf(acc - m);
    float s = e;
#pragma unroll
    for (int o = 32; o > 0; o >>= 1) s += __shfl_xor(s, o);
    out[(size_t)node * 64 + lane] = e / s;
}

extern "C" void kernel_launch(void* const* d_in, const int* in_sizes, int n_in,
                              void* d_out, int out_size, void* d_ws, size_t ws_size,
                              hipStream_t stream) {
    const float* x  = (const float*)d_in[0];
    const int*   ei = (const int*)d_in[1];
    const float* W1 = (const float*)d_in[2];
    const float* b1 = (const float*)d_in[3];
    const float* W2 = (const float*)d_in[4];
    const float* b2 = (const float*)d_in[5];
    float* out = (float*)d_out;

    const int E = in_sizes[1] / 2;   // 800000
    const int N = out_size / 64;     // 50000
    const int* src = ei;
    const int* dst = ei + E;
    const int CH = (N + 255) / 256;  // 196 chunks

    char* ws = (char*)d_ws;
    size_t o = 0;
    auto alloc = [&](size_t bytes) {
        void* p = ws + o;
        o += (bytes + 255) & ~(size_t)255;
        return p;
    };
    int*   cnt        = (int*)alloc((size_t)N * 4);
    int*   chunk_sum  = (int*)alloc((size_t)256 * 4);
    int*   row_start  = (int*)alloc((size_t)(N + 1) * 4);
    int*   cursor     = (int*)alloc((size_t)N * 4);
    int*   csr_src    = (int*)alloc((size_t)E * 4);
    float* csr_w      = (float*)alloc((size_t)E * 4);
    float* dinv       = (float*)alloc((size_t)N * 4);
    _Float16* xw1     = (_Float16*)alloc((size_t)N * 256 * 2);
    float* h1         = (float*)alloc((size_t)N * 256 * 4);
    float* xw2        = (float*)alloc((size_t)N * 64 * 4);
    unsigned short* wt1h = (unsigned short*)alloc((size_t)256 * 512 * 2);
    unsigned short* wt1l = (unsigned short*)alloc((size_t)256 * 512 * 2);
    unsigned short* wt2h = (unsigned short*)alloc((size_t)64 * 256 * 2);
    unsigned short* wt2l = (unsigned short*)alloc((size_t)64 * 256 * 2);
    (void)ws_size; (void)n_in;

    // ---- CSR build + dinv + weight pack (10 stream ops total) ----
    hipMemsetAsync(cnt, 0, (size_t)N * 4, stream);
    k_edge_hist<<<(E + 255) / 256, 256, 0, stream>>>(dst, cnt, E);
    k_chunk_sum<<<CH, 256, 0, stream>>>(cnt, chunk_sum, N);
    k_expand_fused<<<CH, 256, 0, stream>>>(cnt, chunk_sum, row_start, cursor, dinv, N, E, CH);
    k_fill_csr<<<(E + 255) / 256, 256, 0, stream>>>(src, dst, dinv, cursor, csr_src, csr_w, E);
    k_pack_both<<<(512 * 256 + 256 * 64 + 255) / 256, 256, 0, stream>>>(
        W1, wt1h, wt1l, W2, wt2h, wt2l);

    // ---- layer 1: xw1 = x @ W1 (MFMA split, fp16 out), aggregate+ReLU ----
    dim3 g1((N + 127) / 128, 2);
    k_gemm_mfma<128, true><<<g1, 256, 0, stream>>>(x, wt1h, wt1l, xw1, N, 256, 512);
    k_agg256_relu<<<(N + 3) / 4, 256, 0, stream>>>(row_start, csr_src, csr_w, dinv, xw1, b1, h1, N);

    // ---- layer 2: xw2 = h1 @ W2 (MFMA split), aggregate+softmax ----
    dim3 g2((N + 127) / 128, 1);
    k_gemm_mfma<64, false><<<g2, 256, 0, stream>>>(h1, wt2h, wt2l, xw2, N, 64, 256);
    k_agg64_softmax<<<(N + 3) / 4, 256, 0, stream>>>(row_start, csr_src, csr_w, dinv, xw2, b2, out, N);
}

// Round 11
// 409.744 us; speedup vs baseline: 1.3149x; 1.0540x over previous
//
#include <hip/hip_runtime.h>
#include <cstddef>
#include <cstdint>

// ---------------------------------------------------------------------------
// GCN 2-layer forward. Round 14 (= round 12 resubmitted again; rounds 12/13
// died of GPU-acquisition timeout and container-acquire failure — kernel has
// never run. Same precedent as round 2->3 where "container failed twice"
// resolved on resubmission of identical source).
//  - Round 10/11 post-mortem: occupancy lever closed (VGPR cap <100 spills:
//    (256,4)->64 VGPR/264MB spills; (256,3)->84 VGPR/+12MB spills). Back to
//    (256,2); attack the serial staging phase instead.
//  - GEMM = minimum 2-phase pipeline (T3): A staged as RAW F32 via
//    global_load_lds DMA (no reg round-trip, no ds_write, no stage-side
//    convert), double-buffered 2x32KB. Per K-tile: {issue DMA t+1} ->
//    {ds_read + cvt_pk convert + MFMA on t} -> ONE barrier. DMA lands under
//    the MFMA phase, so the vmcnt(0) drain at the barrier is ~free.
//  - Swizzle with linear DMA dest via pre-swizzled per-lane GLOBAL source:
//    chunk c of row r at 16B-unit (c ^ (r&15)); read uses same XOR ->
//    2-way bank aliasing = free.
//  - B: packed fragment-major bf16 hi/lo, direct from L2 (round-9 proven).
//  - Conversion (f32->bf16 hi/lo, 3-pass MFMA) numerically identical to
//    rounds 7-11 (absmax stays 1.22e-4).
//  - CSR fusions (memset/fused-expand/pack_both), fp16 xw1 gather, agg
//    kernels unchanged.
// ---------------------------------------------------------------------------

typedef __attribute__((ext_vector_type(8))) short short8;
typedef __attribute__((ext_vector_type(4))) float f32x4;
typedef __attribute__((ext_vector_type(4))) _Float16 half4;

__device__ inline unsigned short f2bf(float f) {
    unsigned u = __float_as_uint(f);
    unsigned r = (u + 0x7fffu + ((u >> 16) & 1u)) >> 16;  // RNE
    return (unsigned short)r;
}
__device__ inline float bf2f(unsigned short h) {
    return __uint_as_float((unsigned)h << 16);
}

// packs bf16(a) into [15:0], bf16(b) into [31:16]
__device__ inline unsigned cvt_pk_bf16(float a, float b) {
    unsigned r;
    asm("v_cvt_pk_bf16_f32 %0, %1, %2" : "=v"(r) : "v"(a), "v"(b));
    return r;
}

// async global->LDS, 16 B per lane; lds base must be wave-uniform.
__device__ __forceinline__ void lds_dma16(void* lds_wave_base, const void* g) {
    __builtin_amdgcn_global_load_lds(
        (const __attribute__((address_space(1))) unsigned int*)g,
        (__attribute__((address_space(3))) unsigned int*)lds_wave_base,
        16, 0, 0);
}

__global__ void k_edge_hist(const int* __restrict__ dst, int* __restrict__ cnt, int E) {
    int e = blockIdx.x * blockDim.x + threadIdx.x;
    if (e < E) atomicAdd(&cnt[dst[e]], 1);
}

__device__ inline int wave_incl_scan(int v) {
    const int lane = threadIdx.x & 63;
#pragma unroll
    for (int off = 1; off < 64; off <<= 1) {
        int u = __shfl_up(v, off);
        if (lane >= off) v += u;
    }
    return v;
}

__global__ __launch_bounds__(256) void k_chunk_sum(const int* __restrict__ cnt,
                                                   int* __restrict__ chunk_sum, int N) {
    __shared__ int wsum[4];
    const int i = blockIdx.x * 256 + threadIdx.x;
    int v = (i < N) ? cnt[i] : 0;
#pragma unroll
    for (int off = 32; off > 0; off >>= 1) v += __shfl_xor(v, off);
    if ((threadIdx.x & 63) == 0) wsum[threadIdx.x >> 6] = v;
    __syncthreads();
    if (threadIdx.x == 0)
        chunk_sum[blockIdx.x] = wsum[0] + wsum[1] + wsum[2] + wsum[3];
}

// Fused: scan of chunk_sum (redundant per block, CH<=256) + within-chunk
// exclusive scan -> row_start/cursor, + dinv.
__global__ __launch_bounds__(256) void k_expand_fused(
    const int* __restrict__ cnt, const int* __restrict__ chunk_sum,
    int* __restrict__ row_start, int* __restrict__ cursor,
    float* __restrict__ dinv, int N, int E, int CH) {
    __shared__ int wsum[4];
    __shared__ int base_sh;
    const int t = threadIdx.x, lane = t & 63, wid = t >> 6;

    int v = (t < CH) ? chunk_sum[t] : 0;
    int incl = wave_incl_scan(v);
    if (lane == 63) wsum[wid] = incl;
    __syncthreads();
    int cb = 0;
    for (int w2 = 0; w2 < 4; ++w2) { int s = wsum[w2]; if (w2 < wid) cb += s; }
    if (t == (int)blockIdx.x) base_sh = cb + incl - v;
    __syncthreads();
    const int base0 = base_sh;

    const int i = blockIdx.x * 256 + t;
    int c = (i < N) ? cnt[i] : 0;
    int incl2 = wave_incl_scan(c);
    if (lane == 63) wsum[wid] = incl2;
    __syncthreads();
    int b = base0;
    for (int w2 = 0; w2 < 4; ++w2) { int s = wsum[w2]; if (w2 < wid) b += s; }
    const int excl = b + incl2 - c;
    if (i < N) {
        row_start[i] = excl;
        cursor[i]    = excl;
        dinv[i]      = rsqrtf((float)(c + 1));   // +1 self-loop
    }
    if (i == 0) row_start[N] = E;
}

__global__ void k_fill_csr(const int* __restrict__ src, const int* __restrict__ dst,
                           const float* __restrict__ dinv,
                           int* __restrict__ cursor, int* __restrict__ csr_src,
                           float* __restrict__ csr_w, int E) {
    int e = blockIdx.x * blockDim.x + threadIdx.x;
    if (e < E) {
        const int d = dst[e];
        const int s = src[e];
        const int p = atomicAdd(&cursor[d], 1);
        csr_src[p] = s;
        csr_w[p]   = dinv[s] * dinv[d];
    }
}

// Fragment-major pack of BOTH weight matrices in one launch.
// P[nf][K/32][lane][8], lane = (k>>3 & 3)*16 + (n&15), elem j = k&7.
__device__ inline void pack_one(const float* __restrict__ W,
                                unsigned short* __restrict__ Ph,
                                unsigned short* __restrict__ Pl,
                                int i, int K, int N) {
    const int k = i / N, n = i % N;
    const float v = W[i];
    const unsigned short h = f2bf(v);
    const unsigned short l = f2bf(v - bf2f(h));
    const int nf = n >> 4, l15 = n & 15;
    const int kb = k >> 5, l4 = (k >> 3) & 3, j = k & 7;
    const size_t dst = ((((size_t)nf * (K >> 5) + kb) * 64) + l4 * 16 + l15) * 8 + j;
    Ph[dst] = h;
    Pl[dst] = l;
}

__global__ void k_pack_both(const float* __restrict__ W1,
                            unsigned short* __restrict__ P1h,
                            unsigned short* __restrict__ P1l,
                            const float* __restrict__ W2,
                            unsigned short* __restrict__ P2h,
                            unsigned short* __restrict__ P2l) {
    const int i = blockIdx.x * blockDim.x + threadIdx.x;
    constexpr int S1 = 512 * 256;
    constexpr int S2 = 256 * 64;
    if (i < S1)            pack_one(W1, P1h, P1l, i, 512, 256);
    else if (i < S1 + S2)  pack_one(W2, P2h, P2l, i - S1, 256, 64);
}

// C[M,N] = A[M,K] @ B[K,N], bf16x2-split MFMA, 2-phase DMA pipeline.
// A: f32 row-major -> LDS raw f32 via global_load_lds (double-buffered,
//    source-swizzled: chunk c of row r at unit c^(r&15)); converted to
//    bf16 hi/lo at fragment read (cvt_pk).
// B: packed fragment-major bf16 hi/lo (k_pack_both), direct from L2.
// 256 threads = 4 waves 2x2; wave tile = 64 x (BN/2); BK = 64.
template<int BN, bool F16OUT>
__global__ __launch_bounds__(256, 2) void k_gemm_mfma(
    const float* __restrict__ A,
    const unsigned short* __restrict__ Bph,
    const unsigned short* __restrict__ Bpl,
    void* __restrict__ Cv, int M, int N, int K) {
    constexpr int BM = 128, BK = 64;
    constexpr int MF = 4;          // 4 x 16 rows per wave
    constexpr int NF = BN / 32;    // frags over wave's BN/2 cols

    __shared__ float AshF[2 * BM * BK];   // 2 x 32 KB raw f32 A tiles

    const int t    = threadIdx.x;
    const int lane = t & 63;
    const int w    = t >> 6;
    const int wr   = w >> 1;       // 0..1
    const int wc   = w & 1;        // 0..1
    const int l15  = lane & 15;
    const int l4   = lane >> 4;
    const int bm   = blockIdx.x * BM;
    const int bn   = blockIdx.y * BN;

    const int K32     = K >> 5;
    const int nf_base = (bn + wc * (BN / 2)) >> 4;

    f32x4 acc[MF][NF] = {};

    // Stage one BM x BK f32 tile into buf via DMA.
    // Slot su (16B units): row = su>>4, unit p = su&15 holds chunk p^(row&15).
    auto stage = [&](int buf, int k0) {
#pragma unroll
        for (int i = 0; i < 8; ++i) {                 // 8 x 1KB per wave
            const int su  = (w * 8 + i) * 64 + lane;  // 16B-unit slot
            const int row = su >> 4;
            const int c   = (su & 15) ^ (row & 15);   // source chunk
            int gr = bm + row; if (gr > M - 1) gr = M - 1;  // clamp (discarded rows)
            const float* g = A + (size_t)gr * K + k0 + (c << 2);
            float* lbase = &AshF[buf * (BM * BK) + (w * 8 + i) * 256];
            lds_dma16(lbase, g);
        }
    };

    const int NT = K / BK;
    stage(0, 0);
    __syncthreads();   // compiler drains vmcnt before barrier -> tile 0 ready

    for (int ts = 0; ts < NT; ++ts) {
        const int buf  = ts & 1;
        const int fbase = buf * (BM * BK);
        if (ts + 1 < NT) stage(buf ^ 1, (ts + 1) * BK);  // in flight under MFMA

        const int k0 = ts * BK;
#pragma unroll
        for (int kk = 0; kk < BK; kk += 32) {
            const int kb   = kk + l4 * 8;      // f32 k-offset of fragment
            const int u0   = kb >> 2;          // first 16B unit (even)
            const int kb32 = (k0 + kk) >> 5;   // packed-B K/32 index
            short8 bh[NF], bl[NF];
#pragma unroll
            for (int n = 0; n < NF; ++n) {
                const size_t boff =
                    (((size_t)(nf_base + n) * K32 + kb32) * 64 + lane) * 8;
                bh[n] = *(const short8*)(Bph + boff);
                bl[n] = *(const short8*)(Bpl + boff);
            }
#pragma unroll
            for (int m = 0; m < MF; ++m) {
                const int r  = wr * 64 + m * 16 + l15;
                const int p0 = u0 ^ (r & 15);
                const int p1 = (u0 + 1) ^ (r & 15);
                const float4 va = *(const float4*)&AshF[fbase + (r * 16 + p0) * 4];
                const float4 vb = *(const float4*)&AshF[fbase + (r * 16 + p1) * 4];
                const unsigned ph0 = cvt_pk_bf16(va.x, va.y);
                const unsigned ph1 = cvt_pk_bf16(va.z, va.w);
                const unsigned ph2 = cvt_pk_bf16(vb.x, vb.y);
                const unsigned ph3 = cvt_pk_bf16(vb.z, vb.w);
                const unsigned pl0 = cvt_pk_bf16(va.x - __uint_as_float(ph0 << 16),
                                                 va.y - __uint_as_float(ph0 & 0xffff0000u));
                const unsigned pl1 = cvt_pk_bf16(va.z - __uint_as_float(ph1 << 16),
                                                 va.w - __uint_as_float(ph1 & 0xffff0000u));
                const unsigned pl2 = cvt_pk_bf16(vb.x - __uint_as_float(ph2 << 16),
                                                 vb.y - __uint_as_float(ph2 & 0xffff0000u));
                const unsigned pl3 = cvt_pk_bf16(vb.z - __uint_as_float(ph3 << 16),
                                                 vb.w - __uint_as_float(ph3 & 0xffff0000u));
                uint4 hu = make_uint4(ph0, ph1, ph2, ph3);
                uint4 lu = make_uint4(pl0, pl1, pl2, pl3);
                const short8 ah = *(const short8*)&hu;
                const short8 al = *(const short8*)&lu;
#pragma unroll
                for (int n = 0; n < NF; ++n) {
                    acc[m][n] = __builtin_amdgcn_mfma_f32_16x16x32_bf16(ah, bh[n], acc[m][n], 0, 0, 0);
                    acc[m][n] = __builtin_amdgcn_mfma_f32_16x16x32_bf16(ah, bl[n], acc[m][n], 0, 0, 0);
                    acc[m][n] = __builtin_amdgcn_mfma_f32_16x16x32_bf16(al, bh[n], acc[m][n], 0, 0, 0);
                }
            }
        }
        __syncthreads();   // one barrier/tile: drains next-tile DMA (landed
                           // under MFMA) + guards buffer reuse
    }

    // ---- epilogue: C/D layout col = lane&15, row = (lane>>4)*4 + e ----
#pragma unroll
    for (int m = 0; m < MF; ++m) {
        const int row0 = bm + wr * 64 + m * 16 + l4 * 4;
#pragma unroll
        for (int e = 0; e < 4; ++e) {
            const int r = row0 + e;
            if (r < M) {
#pragma unroll
                for (int n = 0; n < NF; ++n) {
                    const size_t ci = (size_t)r * N + bn + wc * (BN / 2) + n * 16 + l15;
                    if constexpr (F16OUT)
                        ((_Float16*)Cv)[ci] = (_Float16)acc[m][n][e];
                    else
                        ((float*)Cv)[ci] = acc[m][n][e];
                }
            }
        }
    }
}

// Layer-1 aggregate: one wave per dst node, F=256, fp16 input (lane -> half4),
// f32 accumulate, unroll x4, f32 output.
__global__ __launch_bounds__(256) void k_agg256_relu(
    const int* __restrict__ row_start, const int* __restrict__ csr_src,
    const float* __restrict__ csr_w, const float* __restrict__ dinv,
    const _Float16* __restrict__ xw, const float* __restrict__ bias,
    float* __restrict__ out, int N) {
    const int node = blockIdx.x * 4 + (threadIdx.x >> 6);
    const int lane = threadIdx.x & 63;
    if (node >= N) return;

    const float dn  = dinv[node];
    const int   beg = row_start[node];
    const int   end = row_start[node + 1];

    const half4 hs = *(const half4*)(xw + (size_t)node * 256 + lane * 4);
    const float wself = dn * dn;
    float4 acc;
    acc.x = (float)hs.x * wself; acc.y = (float)hs.y * wself;
    acc.z = (float)hs.z * wself; acc.w = (float)hs.w * wself;

    int j = beg;
    const int end4 = beg + ((end - beg) & ~3);
    for (; j < end4; j += 4) {
        const int s0 = csr_src[j + 0], s1 = csr_src[j + 1];
        const int s2 = csr_src[j + 2], s3 = csr_src[j + 3];
        const float w0 = csr_w[j + 0], w1 = csr_w[j + 1];
        const float w2 = csr_w[j + 2], w3 = csr_w[j + 3];
        const half4 v0 = *(const half4*)(xw + (size_t)s0 * 256 + lane * 4);
        const half4 v1 = *(const half4*)(xw + (size_t)s1 * 256 + lane * 4);
        const half4 v2 = *(const half4*)(xw + (size_t)s2 * 256 + lane * 4);
        const half4 v3 = *(const half4*)(xw + (size_t)s3 * 256 + lane * 4);
        acc.x = fmaf((float)v0.x, w0, acc.x); acc.y = fmaf((float)v0.y, w0, acc.y);
        acc.z = fmaf((float)v0.z, w0, acc.z); acc.w = fmaf((float)v0.w, w0, acc.w);
        acc.x = fmaf((float)v1.x, w1, acc.x); acc.y = fmaf((float)v1.y, w1, acc.y);
        acc.z = fmaf((float)v1.z, w1, acc.z); acc.w = fmaf((float)v1.w, w1, acc.w);
        acc.x = fmaf((float)v2.x, w2, acc.x); acc.y = fmaf((float)v2.y, w2, acc.y);
        acc.z = fmaf((float)v2.z, w2, acc.z); acc.w = fmaf((float)v2.w, w2, acc.w);
        acc.x = fmaf((float)v3.x, w3, acc.x); acc.y = fmaf((float)v3.y, w3, acc.y);
        acc.z = fmaf((float)v3.z, w3, acc.z); acc.w = fmaf((float)v3.w, w3, acc.w);
    }
    for (; j < end; ++j) {
        const int   s = csr_src[j];
        const float w = csr_w[j];
        const half4 v = *(const half4*)(xw + (size_t)s * 256 + lane * 4);
        acc.x = fmaf((float)v.x, w, acc.x); acc.y = fmaf((float)v.y, w, acc.y);
        acc.z = fmaf((float)v.z, w, acc.z); acc.w = fmaf((float)v.w, w, acc.w);
    }

    const float4 b = ((const float4*)bias)[lane];
    acc.x = fmaxf(acc.x + b.x, 0.f);
    acc.y = fmaxf(acc.y + b.y, 0.f);
    acc.z = fmaxf(acc.z + b.z, 0.f);
    acc.w = fmaxf(acc.w + b.w, 0.f);
    *(float4*)(out + (size_t)node * 256 + lane * 4) = acc;
}

// Layer-2 aggregate + bias + softmax: one wave per dst node, F=64, unroll x4.
__global__ __launch_bounds__(256) void k_agg64_softmax(
    const int* __restrict__ row_start, const int* __restrict__ csr_src,
    const float* __restrict__ csr_w, const float* __restrict__ dinv,
    const float* __restrict__ xw, const float* __restrict__ bias,
    float* __restrict__ out, int N) {
    const int node = blockIdx.x * 4 + (threadIdx.x >> 6);
    const int lane = threadIdx.x & 63;
    if (node >= N) return;

    const float dn  = dinv[node];
    const int   beg = row_start[node];
    const int   end = row_start[node + 1];

    float acc = xw[(size_t)node * 64 + lane] * dn * dn;
    int j = beg;
    const int end4 = beg + ((end - beg) & ~3);
    for (; j < end4; j += 4) {
        const int s0 = csr_src[j + 0], s1 = csr_src[j + 1];
        const int s2 = csr_src[j + 2], s3 = csr_src[j + 3];
        const float w0 = csr_w[j + 0], w1 = csr_w[j + 1];
        const float w2 = csr_w[j + 2], w3 = csr_w[j + 3];
        const float v0 = xw[(size_t)s0 * 64 + lane];
        const float v1 = xw[(size_t)s1 * 64 + lane];
        const float v2 = xw[(size_t)s2 * 64 + lane];
        const float v3 = xw[(size_t)s3 * 64 + lane];
        acc = fmaf(v0, w0, acc);
        acc = fmaf(v1, w1, acc);
        acc = fmaf(v2, w2, acc);
        acc = fmaf(v3, w3, acc);
    }
    for (; j < end; ++j)
        acc = fmaf(xw[(size_t)csr_src[j] * 64 + lane], csr_w[j], acc);

    acc += bias[lane];

    float m = acc;
#pragma unroll
    for (int o = 32; o > 0; o >>= 1) m = fmaxf(m, __shfl_xor(m, o));
    const float e = expf(acc - m);
    float s = e;
#pragma unroll
    for (int o = 32; o > 0; o >>= 1) s += __shfl_xor(s, o);
    out[(size_t)node * 64 + lane] = e / s;
}

extern "C" void kernel_launch(void* const* d_in, const int* in_sizes, int n_in,
                              void* d_out, int out_size, void* d_ws, size_t ws_size,
                              hipStream_t stream) {
    const float* x  = (const float*)d_in[0];
    const int*   ei = (const int*)d_in[1];
    const float* W1 = (const float*)d_in[2];
    const float* b1 = (const float*)d_in[3];
    const float* W2 = (const float*)d_in[4];
    const float* b2 = (const float*)d_in[5];
    float* out = (float*)d_out;

    const int E = in_sizes[1] / 2;   // 800000
    const int N = out_size / 64;     // 50000
    const int* src = ei;
    const int* dst = ei + E;
    const int CH = (N + 255) / 256;  // 196 chunks

    char* ws = (char*)d_ws;
    size_t o = 0;
    auto alloc = [&](size_t bytes) {
        void* p = ws + o;
        o += (bytes + 255) & ~(size_t)255;
        return p;
    };
    int*   cnt        = (int*)alloc((size_t)N * 4);
    int*   chunk_sum  = (int*)alloc((size_t)256 * 4);
    int*   row_start  = (int*)alloc((size_t)(N + 1) * 4);
    int*   cursor     = (int*)alloc((size_t)N * 4);
    int*   csr_src    = (int*)alloc((size_t)E * 4);
    float* csr_w      = (float*)alloc((size_t)E * 4);
    float* dinv       = (float*)alloc((size_t)N * 4);
    _Float16* xw1     = (_Float16*)alloc((size_t)N * 256 * 2);
    float* h1         = (float*)alloc((size_t)N * 256 * 4);
    float* xw2        = (float*)alloc((size_t)N * 64 * 4);
    unsigned short* wt1h = (unsigned short*)alloc((size_t)256 * 512 * 2);
    unsigned short* wt1l = (unsigned short*)alloc((size_t)256 * 512 * 2);
    unsigned short* wt2h = (unsigned short*)alloc((size_t)64 * 256 * 2);
    unsigned short* wt2l = (unsigned short*)alloc((size_t)64 * 256 * 2);
    (void)ws_size; (void)n_in;

    // ---- CSR build + dinv + weight pack ----
    hipMemsetAsync(cnt, 0, (size_t)N * 4, stream);
    k_edge_hist<<<(E + 255) / 256, 256, 0, stream>>>(dst, cnt, E);
    k_chunk_sum<<<CH, 256, 0, stream>>>(cnt, chunk_sum, N);
    k_expand_fused<<<CH, 256, 0, stream>>>(cnt, chunk_sum, row_start, cursor, dinv, N, E, CH);
    k_fill_csr<<<(E + 255) / 256, 256, 0, stream>>>(src, dst, dinv, cursor, csr_src, csr_w, E);
    k_pack_both<<<(512 * 256 + 256 * 64 + 255) / 256, 256, 0, stream>>>(
        W1, wt1h, wt1l, W2, wt2h, wt2l);

    // ---- layer 1: xw1 = x @ W1 (MFMA split, fp16 out), aggregate+ReLU ----
    dim3 g1((N + 127) / 128, 2);
    k_gemm_mfma<128, true><<<g1, 256, 0, stream>>>(x, wt1h, wt1l, xw1, N, 256, 512);
    k_agg256_relu<<<(N + 3) / 4, 256, 0, stream>>>(row_start, csr_src, csr_w, dinv, xw1, b1, h1, N);

    // ---- layer 2: xw2 = h1 @ W2 (MFMA split), aggregate+softmax ----
    dim3 g2((N + 127) / 128, 1);
    k_gemm_mfma<64, false><<<g2, 256, 0, stream>>>(h1, wt2h, wt2l, xw2, N, 64, 256);
    k_agg64_softmax<<<(N + 3) / 4, 256, 0, stream>>>(row_start, csr_src, csr_w, dinv, xw2, b2, out, N);
}

// Round 13
// 386.993 us; speedup vs baseline: 1.3922x; 1.0588x over previous
//
#include <hip/hip_runtime.h>
#include <cstddef>
#include <cstdint>

// ---------------------------------------------------------------------------
// GCN 2-layer forward. Round 16 — recombine best hardware-verified parts:
//  - Round 12 (BK=32 DMA, 4 blk/CU) FAILED correctness (7.3e-4, nondet);
//    algebra re-audit found no logical bug -> suspected codegen effect;
//    variant abandoned per post-mortem discipline.
//  - GEMM = round-7 kernel VERBATIM (68-70 us measured, absmax 1.22e-4):
//    reg-pipelined one K-tile ahead, cvt_pk bf16 hi/lo split at stage,
//    XOR-swizzled 64KB LDS, (256,2). B as bf16 hi/lo [N][K] (transposed).
//  - CSR side = rounds 10/11 fusions (hw-verified): hipMemsetAsync,
//    edge_hist, chunk_sum, fused expand+dinv, fill_csr, ONE pack kernel
//    (k_split_both -> [N][K] layout for both W1/W2).
//  - agg256/agg64: x8 unroll added. Ascending-j single-acc fmaf chain is
//    preserved -> bit-identical numerics, deeper gather MLP.
//  - fp16 xw1 gather unchanged.
// ---------------------------------------------------------------------------

typedef __attribute__((ext_vector_type(8))) short short8;
typedef __attribute__((ext_vector_type(4))) float f32x4;
typedef __attribute__((ext_vector_type(4))) _Float16 half4;

__device__ inline unsigned short f2bf(float f) {
    unsigned u = __float_as_uint(f);
    unsigned r = (u + 0x7fffu + ((u >> 16) & 1u)) >> 16;  // RNE
    return (unsigned short)r;
}
__device__ inline float bf2f(unsigned short h) {
    return __uint_as_float((unsigned)h << 16);
}

// packs bf16(a) into [15:0], bf16(b) into [31:16]
__device__ inline unsigned cvt_pk_bf16(float a, float b) {
    unsigned r;
    asm("v_cvt_pk_bf16_f32 %0, %1, %2" : "=v"(r) : "v"(a), "v"(b));
    return r;
}

__global__ void k_edge_hist(const int* __restrict__ dst, int* __restrict__ cnt, int E) {
    int e = blockIdx.x * blockDim.x + threadIdx.x;
    if (e < E) atomicAdd(&cnt[dst[e]], 1);
}

__device__ inline int wave_incl_scan(int v) {
    const int lane = threadIdx.x & 63;
#pragma unroll
    for (int off = 1; off < 64; off <<= 1) {
        int u = __shfl_up(v, off);
        if (lane >= off) v += u;
    }
    return v;
}

__global__ __launch_bounds__(256) void k_chunk_sum(const int* __restrict__ cnt,
                                                   int* __restrict__ chunk_sum, int N) {
    __shared__ int wsum[4];
    const int i = blockIdx.x * 256 + threadIdx.x;
    int v = (i < N) ? cnt[i] : 0;
#pragma unroll
    for (int off = 32; off > 0; off >>= 1) v += __shfl_xor(v, off);
    if ((threadIdx.x & 63) == 0) wsum[threadIdx.x >> 6] = v;
    __syncthreads();
    if (threadIdx.x == 0)
        chunk_sum[blockIdx.x] = wsum[0] + wsum[1] + wsum[2] + wsum[3];
}

// Fused: scan of chunk_sum (redundant per block, CH<=256) + within-chunk
// exclusive scan -> row_start/cursor, + dinv.
__global__ __launch_bounds__(256) void k_expand_fused(
    const int* __restrict__ cnt, const int* __restrict__ chunk_sum,
    int* __restrict__ row_start, int* __restrict__ cursor,
    float* __restrict__ dinv, int N, int E, int CH) {
    __shared__ int wsum[4];
    __shared__ int base_sh;
    const int t = threadIdx.x, lane = t & 63, wid = t >> 6;

    int v = (t < CH) ? chunk_sum[t] : 0;
    int incl = wave_incl_scan(v);
    if (lane == 63) wsum[wid] = incl;
    __syncthreads();
    int cb = 0;
    for (int w2 = 0; w2 < 4; ++w2) { int s = wsum[w2]; if (w2 < wid) cb += s; }
    if (t == (int)blockIdx.x) base_sh = cb + incl - v;
    __syncthreads();
    const int base0 = base_sh;

    const int i = blockIdx.x * 256 + t;
    int c = (i < N) ? cnt[i] : 0;
    int incl2 = wave_incl_scan(c);
    if (lane == 63) wsum[wid] = incl2;
    __syncthreads();
    int b = base0;
    for (int w2 = 0; w2 < 4; ++w2) { int s = wsum[w2]; if (w2 < wid) b += s; }
    const int excl = b + incl2 - c;
    if (i < N) {
        row_start[i] = excl;
        cursor[i]    = excl;
        dinv[i]      = rsqrtf((float)(c + 1));   // +1 self-loop
    }
    if (i == 0) row_start[N] = E;
}

__global__ void k_fill_csr(const int* __restrict__ src, const int* __restrict__ dst,
                           const float* __restrict__ dinv,
                           int* __restrict__ cursor, int* __restrict__ csr_src,
                           float* __restrict__ csr_w, int E) {
    int e = blockIdx.x * blockDim.x + threadIdx.x;
    if (e < E) {
        const int d = dst[e];
        const int s = src[e];
        const int p = atomicAdd(&cursor[d], 1);
        csr_src[p] = s;
        csr_w[p]   = dinv[s] * dinv[d];
    }
}

// W[K][N] f32 -> Wt_hi/Wt_lo[N][K] bf16 (transposed + split), both matrices
// in one launch.
__device__ inline void split_one(const float* __restrict__ W,
                                 unsigned short* __restrict__ Wh,
                                 unsigned short* __restrict__ Wl,
                                 int i, int K, int N) {
    const int k = i / N, n = i % N;
    const float v = W[i];
    const unsigned short h = f2bf(v);
    const unsigned short l = f2bf(v - bf2f(h));
    Wh[(size_t)n * K + k] = h;
    Wl[(size_t)n * K + k] = l;
}

__global__ void k_split_both(const float* __restrict__ W1,
                             unsigned short* __restrict__ P1h,
                             unsigned short* __restrict__ P1l,
                             const float* __restrict__ W2,
                             unsigned short* __restrict__ P2h,
                             unsigned short* __restrict__ P2l) {
    const int i = blockIdx.x * blockDim.x + threadIdx.x;
    constexpr int S1 = 512 * 256;
    constexpr int S2 = 256 * 64;
    if (i < S1)            split_one(W1, P1h, P1l, i, 512, 256);
    else if (i < S1 + S2)  split_one(W2, P2h, P2l, i - S1, 256, 64);
}

// C[M,N] = A[M,K] @ B[K,N] using bf16x2-split MFMA, 1-step pipelined staging.
// Round-7 kernel verbatim (68-70 us measured on GEMM1, absmax 1.22e-4).
// A: f32 row-major (split in-kernel via v_cvt_pk_bf16_f32).
// Bh/Bl: bf16 [N][K] (pre-transposed). 256 threads = 4 waves 2x2.
// LDS swizzle: ushort index ^ ((row&7)<<3).
template<int BM, int BN, int BK, bool F16OUT>
__global__ __launch_bounds__(256, 2) void k_gemm_mfma(
    const float* __restrict__ A,
    const unsigned short* __restrict__ Bh,
    const unsigned short* __restrict__ Bl,
    void* __restrict__ Cv, int M, int N, int K) {
    static_assert(BM == 128 && BK == 64, "tuned for BM=128, BK=64");
    constexpr int MF  = 4;                    // 4 x 16 rows per wave
    constexpr int NF  = BN / 32;              // frags over wave's BN/2 cols
    constexpr int NA4 = BM * BK / 4 / 256;    // 8 float4 per thread (A tile)
    constexpr int NB8 = BN * BK / 8 / 256;    // short8 per thread (B tile)

    __shared__ unsigned short Ash[BM * BK];
    __shared__ unsigned short Asl[BM * BK];
    __shared__ unsigned short Bsh[BN * BK];
    __shared__ unsigned short Bsl[BN * BK];

    const int t    = threadIdx.x;
    const int lane = t & 63;
    const int w    = t >> 6;
    const int wr   = w >> 1;      // 0..1
    const int wc   = w & 1;       // 0..1
    const int l15  = lane & 15;
    const int l4   = lane >> 4;
    const int bm   = blockIdx.x * BM;
    const int bn   = blockIdx.y * BN;

    f32x4 acc[MF][NF] = {};

    // raw tile data in flight (loaded one K-step ahead)
    float4 araw[NA4];
    short8 brawh[NB8], brawl[NB8];

    auto issue_loads = [&](int k0) {
#pragma unroll
        for (int i = 0; i < NA4; ++i) {
            const int idx = t + i * 256;
            const int ar  = idx >> 4;         // 0..BM-1
            const int ac  = (idx & 15) * 4;   // 0..60
            const int am  = bm + ar;
            araw[i] = (am < M) ? *(const float4*)(A + (size_t)am * K + k0 + ac)
                               : make_float4(0.f, 0.f, 0.f, 0.f);
        }
#pragma unroll
        for (int i = 0; i < NB8; ++i) {
            const int idx = t + i * 256;
            const int br  = idx >> 3;
            const int bc  = (idx & 7) * 8;
            const size_t g = (size_t)(bn + br) * K + k0 + bc;
            brawh[i] = *(const short8*)(Bh + g);
            brawl[i] = *(const short8*)(Bl + g);
        }
    };

    auto stage_to_lds = [&]() {
#pragma unroll
        for (int i = 0; i < NA4; ++i) {
            const int idx = t + i * 256;
            const int ar  = idx >> 4;
            const int ac  = (idx & 15) * 4;
            const float4 v = araw[i];
            const unsigned ph0 = cvt_pk_bf16(v.x, v.y);
            const unsigned ph1 = cvt_pk_bf16(v.z, v.w);
            const float h0 = __uint_as_float(ph0 << 16);
            const float h1 = __uint_as_float(ph0 & 0xffff0000u);
            const float h2 = __uint_as_float(ph1 << 16);
            const float h3 = __uint_as_float(ph1 & 0xffff0000u);
            const unsigned pl0 = cvt_pk_bf16(v.x - h0, v.y - h1);
            const unsigned pl1 = cvt_pk_bf16(v.z - h2, v.w - h3);
            const int si = (ar * BK + ac) ^ ((ar & 7) << 3);
            *(uint2*)&Ash[si] = make_uint2(ph0, ph1);
            *(uint2*)&Asl[si] = make_uint2(pl0, pl1);
        }
#pragma unroll
        for (int i = 0; i < NB8; ++i) {
            const int idx = t + i * 256;
            const int br  = idx >> 3;
            const int bc  = (idx & 7) * 8;
            const int si  = (br * BK + bc) ^ ((br & 7) << 3);
            *(short8*)&Bsh[si] = brawh[i];
            *(short8*)&Bsl[si] = brawl[i];
        }
    };

    const int NT = K / BK;
    issue_loads(0);
    for (int ts = 0; ts < NT; ++ts) {
        stage_to_lds();                              // consumes raw tile ts
        if (ts + 1 < NT) issue_loads((ts + 1) * BK); // in flight across MFMA
        __syncthreads();

#pragma unroll
        for (int kk = 0; kk < BK; kk += 32) {
            const int kb = kk + l4 * 8;
            short8 bh[NF], bl[NF];
#pragma unroll
            for (int n = 0; n < NF; ++n) {
                const int col = wc * (BN / 2) + n * 16 + l15;
                const int si  = (col * BK + kb) ^ ((col & 7) << 3);
                bh[n] = *(const short8*)&Bsh[si];
                bl[n] = *(const short8*)&Bsl[si];
            }
#pragma unroll
            for (int m = 0; m < MF; ++m) {
                const int row = wr * 64 + m * 16 + l15;
                const int si  = (row * BK + kb) ^ ((row & 7) << 3);
                const short8 ah = *(const short8*)&Ash[si];
                const short8 al = *(const short8*)&Asl[si];
#pragma unroll
                for (int n = 0; n < NF; ++n) {
                    acc[m][n] = __builtin_amdgcn_mfma_f32_16x16x32_bf16(ah, bh[n], acc[m][n], 0, 0, 0);
                    acc[m][n] = __builtin_amdgcn_mfma_f32_16x16x32_bf16(ah, bl[n], acc[m][n], 0, 0, 0);
                    acc[m][n] = __builtin_amdgcn_mfma_f32_16x16x32_bf16(al, bh[n], acc[m][n], 0, 0, 0);
                }
            }
        }
        __syncthreads();
    }

    // ---- epilogue: C/D layout col = lane&15, row = (lane>>4)*4 + e ----
#pragma unroll
    for (int m = 0; m < MF; ++m) {
        const int row0 = bm + wr * 64 + m * 16 + l4 * 4;
#pragma unroll
        for (int e = 0; e < 4; ++e) {
            const int r = row0 + e;
            if (r < M) {
#pragma unroll
                for (int n = 0; n < NF; ++n) {
                    const size_t ci = (size_t)r * N + bn + wc * (BN / 2) + n * 16 + l15;
                    if constexpr (F16OUT)
                        ((_Float16*)Cv)[ci] = (_Float16)acc[m][n][e];
                    else
                        ((float*)Cv)[ci] = acc[m][n][e];
                }
            }
        }
    }
}

// Layer-1 aggregate: one wave per dst node, F=256, fp16 input (lane -> half4),
// f32 accumulate, unroll x8 (ascending-j chain: bit-identical numerics).
__global__ __launch_bounds__(256) void k_agg256_relu(
    const int* __restrict__ row_start, const int* __restrict__ csr_src,
    const float* __restrict__ csr_w, const float* __restrict__ dinv,
    const _Float16* __restrict__ xw, const float* __restrict__ bias,
    float* __restrict__ out, int N) {
    const int node = blockIdx.x * 4 + (threadIdx.x >> 6);
    const int lane = threadIdx.x & 63;
    if (node >= N) return;

    const float dn  = dinv[node];
    const int   beg = row_start[node];
    const int   end = row_start[node + 1];

    const half4 hs = *(const half4*)(xw + (size_t)node * 256 + lane * 4);
    const float wself = dn * dn;
    float4 acc;
    acc.x = (float)hs.x * wself; acc.y = (float)hs.y * wself;
    acc.z = (float)hs.z * wself; acc.w = (float)hs.w * wself;

    int j = beg;
    const int end8 = beg + ((end - beg) & ~7);
    for (; j < end8; j += 8) {
        int   s[8];
        float wgt[8];
        half4 v[8];
#pragma unroll
        for (int q = 0; q < 8; ++q) { s[q] = csr_src[j + q]; wgt[q] = csr_w[j + q]; }
#pragma unroll
        for (int q = 0; q < 8; ++q)
            v[q] = *(const half4*)(xw + (size_t)s[q] * 256 + lane * 4);
#pragma unroll
        for (int q = 0; q < 8; ++q) {
            acc.x = fmaf((float)v[q].x, wgt[q], acc.x);
            acc.y = fmaf((float)v[q].y, wgt[q], acc.y);
            acc.z = fmaf((float)v[q].z, wgt[q], acc.z);
            acc.w = fmaf((float)v[q].w, wgt[q], acc.w);
        }
    }
    const int end4 = beg + ((end - beg) & ~3);
    for (; j < end4; j += 4) {
        const int s0 = csr_src[j + 0], s1 = csr_src[j + 1];
        const int s2 = csr_src[j + 2], s3 = csr_src[j + 3];
        const float w0 = csr_w[j + 0], w1 = csr_w[j + 1];
        const float w2 = csr_w[j + 2], w3 = csr_w[j + 3];
        const half4 v0 = *(const half4*)(xw + (size_t)s0 * 256 + lane * 4);
        const half4 v1 = *(const half4*)(xw + (size_t)s1 * 256 + lane * 4);
        const half4 v2 = *(const half4*)(xw + (size_t)s2 * 256 + lane * 4);
        const half4 v3 = *(const half4*)(xw + (size_t)s3 * 256 + lane * 4);
        acc.x = fmaf((float)v0.x, w0, acc.x); acc.y = fmaf((float)v0.y, w0, acc.y);
        acc.z = fmaf((float)v0.z, w0, acc.z); acc.w = fmaf((float)v0.w, w0, acc.w);
        acc.x = fmaf((float)v1.x, w1, acc.x); acc.y = fmaf((float)v1.y, w1, acc.y);
        acc.z = fmaf((float)v1.z, w1, acc.z); acc.w = fmaf((float)v1.w, w1, acc.w);
        acc.x = fmaf((float)v2.x, w2, acc.x); acc.y = fmaf((float)v2.y, w2, acc.y);
        acc.z = fmaf((float)v2.z, w2, acc.z); acc.w = fmaf((float)v2.w, w2, acc.w);
        acc.x = fmaf((float)v3.x, w3, acc.x); acc.y = fmaf((float)v3.y, w3, acc.y);
        acc.z = fmaf((float)v3.z, w3, acc.z); acc.w = fmaf((float)v3.w, w3, acc.w);
    }
    for (; j < end; ++j) {
        const int   s = csr_src[j];
        const float w = csr_w[j];
        const half4 v = *(const half4*)(xw + (size_t)s * 256 + lane * 4);
        acc.x = fmaf((float)v.x, w, acc.x); acc.y = fmaf((float)v.y, w, acc.y);
        acc.z = fmaf((float)v.z, w, acc.z); acc.w = fmaf((float)v.w, w, acc.w);
    }

    const float4 b = ((const float4*)bias)[lane];
    acc.x = fmaxf(acc.x + b.x, 0.f);
    acc.y = fmaxf(acc.y + b.y, 0.f);
    acc.z = fmaxf(acc.z + b.z, 0.f);
    acc.w = fmaxf(acc.w + b.w, 0.f);
    *(float4*)(out + (size_t)node * 256 + lane * 4) = acc;
}

// Layer-2 aggregate + bias + softmax: one wave per dst node, F=64, unroll x8.
__global__ __launch_bounds__(256) void k_agg64_softmax(
    const int* __restrict__ row_start, const int* __restrict__ csr_src,
    const float* __restrict__ csr_w, const float* __restrict__ dinv,
    const float* __restrict__ xw, const float* __restrict__ bias,
    float* __restrict__ out, int N) {
    const int node = blockIdx.x * 4 + (threadIdx.x >> 6);
    const int lane = threadIdx.x & 63;
    if (node >= N) return;

    const float dn  = dinv[node];
    const int   beg = row_start[node];
    const int   end = row_start[node + 1];

    float acc = xw[(size_t)node * 64 + lane] * dn * dn;
    int j = beg;
    const int end8 = beg + ((end - beg) & ~7);
    for (; j < end8; j += 8) {
        int   s[8];
        float wgt[8], v[8];
#pragma unroll
        for (int q = 0; q < 8; ++q) { s[q] = csr_src[j + q]; wgt[q] = csr_w[j + q]; }
#pragma unroll
        for (int q = 0; q < 8; ++q) v[q] = xw[(size_t)s[q] * 64 + lane];
#pragma unroll
        for (int q = 0; q < 8; ++q) acc = fmaf(v[q], wgt[q], acc);
    }
    const int end4 = beg + ((end - beg) & ~3);
    for (; j < end4; j += 4) {
        const int s0 = csr_src[j + 0], s1 = csr_src[j + 1];
        const int s2 = csr_src[j + 2], s3 = csr_src[j + 3];
        const float w0 = csr_w[j + 0], w1 = csr_w[j + 1];
        const float w2 = csr_w[j + 2], w3 = csr_w[j + 3];
        const float v0 = xw[(size_t)s0 * 64 + lane];
        const float v1 = xw[(size_t)s1 * 64 + lane];
        const float v2 = xw[(size_t)s2 * 64 + lane];
        const float v3 = xw[(size_t)s3 * 64 + lane];
        acc = fmaf(v0, w0, acc);
        acc = fmaf(v1, w1, acc);
        acc = fmaf(v2, w2, acc);
        acc = fmaf(v3, w3, acc);
    }
    for (; j < end; ++j)
        acc = fmaf(xw[(size_t)csr_src[j] * 64 + lane], csr_w[j], acc);

    acc += bias[lane];

    float m = acc;
#pragma unroll
    for (int o = 32; o > 0; o >>= 1) m = fmaxf(m, __shfl_xor(m, o));
    const float e = expf(acc - m);
    float s = e;
#pragma unroll
    for (int o = 32; o > 0; o >>= 1) s += __shfl_xor(s, o);
    out[(size_t)node * 64 + lane] = e / s;
}

extern "C" void kernel_launch(void* const* d_in, const int* in_sizes, int n_in,
                              void* d_out, int out_size, void* d_ws, size_t ws_size,
                              hipStream_t stream) {
    const float* x  = (const float*)d_in[0];
    const int*   ei = (const int*)d_in[1];
    const float* W1 = (const float*)d_in[2];
    const float* b1 = (const float*)d_in[3];
    const float* W2 = (const float*)d_in[4];
    const float* b2 = (const float*)d_in[5];
    float* out = (float*)d_out;

    const int E = in_sizes[1] / 2;   // 800000
    const int N = out_size / 64;     // 50000
    const int* src = ei;
    const int* dst = ei + E;
    const int CH = (N + 255) / 256;  // 196 chunks

    char* ws = (char*)d_ws;
    size_t o = 0;
    auto alloc = [&](size_t bytes) {
        void* p = ws + o;
        o += (bytes + 255) & ~(size_t)255;
        return p;
    };
    int*   cnt        = (int*)alloc((size_t)N * 4);
    int*   chunk_sum  = (int*)alloc((size_t)256 * 4);
    int*   row_start  = (int*)alloc((size_t)(N + 1) * 4);
    int*   cursor     = (int*)alloc((size_t)N * 4);
    int*   csr_src    = (int*)alloc((size_t)E * 4);
    float* csr_w      = (float*)alloc((size_t)E * 4);
    float* dinv       = (float*)alloc((size_t)N * 4);
    _Float16* xw1     = (_Float16*)alloc((size_t)N * 256 * 2);
    float* h1         = (float*)alloc((size_t)N * 256 * 4);
    float* xw2        = (float*)alloc((size_t)N * 64 * 4);
    unsigned short* wt1h = (unsigned short*)alloc((size_t)256 * 512 * 2);
    unsigned short* wt1l = (unsigned short*)alloc((size_t)256 * 512 * 2);
    unsigned short* wt2h = (unsigned short*)alloc((size_t)64 * 256 * 2);
    unsigned short* wt2l = (unsigned short*)alloc((size_t)64 * 256 * 2);
    (void)ws_size; (void)n_in;

    // ---- CSR build + dinv + weight split (fused launches) ----
    hipMemsetAsync(cnt, 0, (size_t)N * 4, stream);
    k_edge_hist<<<(E + 255) / 256, 256, 0, stream>>>(dst, cnt, E);
    k_chunk_sum<<<CH, 256, 0, stream>>>(cnt, chunk_sum, N);
    k_expand_fused<<<CH, 256, 0, stream>>>(cnt, chunk_sum, row_start, cursor, dinv, N, E, CH);
    k_fill_csr<<<(E + 255) / 256, 256, 0, stream>>>(src, dst, dinv, cursor, csr_src, csr_w, E);
    k_split_both<<<(512 * 256 + 256 * 64 + 255) / 256, 256, 0, stream>>>(
        W1, wt1h, wt1l, W2, wt2h, wt2l);

    // ---- layer 1: xw1 = x @ W1 (MFMA split, fp16 out), aggregate+ReLU ----
    dim3 g1((N + 127) / 128, 2);
    k_gemm_mfma<128, 128, 64, true><<<g1, 256, 0, stream>>>(x, wt1h, wt1l, xw1, N, 256, 512);
    k_agg256_relu<<<(N + 3) / 4, 256, 0, stream>>>(row_start, csr_src, csr_w, dinv, xw1, b1, h1, N);

    // ---- layer 2: xw2 = h1 @ W2 (MFMA split), aggregate+softmax ----
    dim3 g2((N + 127) / 128, 1);
    k_gemm_mfma<128, 64, 64, false><<<g2, 256, 0, stream>>>(h1, wt2h, wt2l, xw2, N, 64, 256);
    k_agg64_softmax<<<(N + 3) / 4, 256, 0, stream>>>(row_start, csr_src, csr_w, dinv, xw2, b2, out, N);
}